// Round 7
// baseline (722.151 us; speedup 1.0000x reference)
//
#include <hip/hip_runtime.h>
#include <cstddef>

#define HID 64
#define TT 64
#define NFEAT 8
#define TOUTC 12
#define SPB 32          // 2 groups x 16 seqs
#define NBLK 256
#define NTHR 256

typedef float f4 __attribute__((ext_vector_type(4)));
typedef _Float16 h8 __attribute__((ext_vector_type(8)));
typedef unsigned int u32;
typedef unsigned long long u64;

#define MFMA16 __builtin_amdgcn_mfma_f32_16x16x32_f16

__device__ __forceinline__ float sigm(float x)  { return 1.0f / (1.0f + __expf(-x)); }
__device__ __forceinline__ float tanh_(float x) { return 1.0f - 2.0f / (__expf(2.0f * x) + 1.0f); }

__device__ __forceinline__ void splitf16(const float* v, h8& hi, h8& lo) {
#pragma unroll
    for (int j = 0; j < 8; ++j) {
        _Float16 h = (_Float16)v[j];
        hi[j] = h;
        lo[j] = (_Float16)(v[j] - (float)h);
    }
}

// raw barrier: order LDS only; vmcnt (ws prefetch/stores) stays in flight
#define RAW_BAR() do {                                          \
    asm volatile("s_waitcnt lgkmcnt(0)" ::: "memory");          \
    __builtin_amdgcn_s_barrier();                               \
    __builtin_amdgcn_sched_barrier(0);                          \
} while (0)

// LDS: zh group A [2][16][64] fp16 @0 (4096B), group B @4096; hs f32[32][68] @8192.
// zh byte = plane*2048 + s*128 + elem*2, XOR-swizzle ^= (s&7)<<4.
// ws: fp16 [seq][t][HID], double-buffered (layer l reads buf[(l+1)&1], writes buf[l&1]).
//
// MFMA 16x16x32 f16: M = gate rows (4 tiles i,f,g,o x wave's 16 hidden units),
// N = 16 seqs (per group), K = [x (KSX*32); h (2*32)].
// A frag: row=l&15, k=8*(l>>4)+j. B frag: col=l&15, same k. C/D: col=l&15, row=4*(l>>4)+r.
// 4 chains/gate: c1 = bias + Whi*x + Whi_h*h[kk0]; c2 = Wlo*x + Whi_h*h[kk1];
//                c3 = Wlo_h*h[kk0]; c4 = Wlo_h*h[kk1]   (all h-MFMAs depth-1 from h)
template<int KSX, bool FIRST, bool LAST>
__device__ __forceinline__ void run_layer(
    const float* __restrict__ Wih, const float* __restrict__ Whh,
    const float* __restrict__ bi,  const float* __restrict__ bh_,
    const float* __restrict__ Xj,
    const unsigned short* __restrict__ rbuf, unsigned short* __restrict__ wbuf,
    char* zh0, float* hs, int tid, int seq0)
{
    constexpr int NKS = KSX + 2;
    const int lane = tid & 63;
    const int wv   = tid >> 6;
    const int cs   = lane & 15;
    const int rq   = lane >> 4;
    const int hb   = 16 * wv + 4 * rq;
    const int swz  = (cs & 7) << 4;
    const int seqA = seq0 + cs;
    const int seqB = seq0 + 16 + cs;
    char* zh1 = zh0 + 4096;

    f4 z4 = {0.f, 0.f, 0.f, 0.f};

    // ---- weight A-fragments (fp16 hi/lo) ----
    h8 Ah[4][NKS], Al[4][NKS];
#pragma unroll
    for (int a = 0; a < 4; ++a) {
        const int row = 64 * a + 16 * wv + cs;
#pragma unroll
        for (int ks = 0; ks < NKS; ++ks) {
            float v[8];
            if (ks < KSX) {
                if (FIRST) {
                    const float* p = Wih + (size_t)row * NFEAT;
#pragma unroll
                    for (int j = 0; j < 8; ++j) v[j] = (rq == 0) ? p[j] : 0.0f;
                } else {
                    const float* p = Wih + (size_t)row * HID + 32 * ks + 8 * rq;
#pragma unroll
                    for (int j = 0; j < 8; ++j) v[j] = p[j];
                }
            } else {
                const float* p = Whh + (size_t)row * HID + 32 * (ks - KSX) + 8 * rq;
#pragma unroll
                for (int j = 0; j < 8; ++j) v[j] = p[j];
            }
            splitf16(v, Ah[a][ks], Al[a][ks]);
        }
    }

    // ---- bias (C/D layout) ----
    f4 bias[4];
#pragma unroll
    for (int a = 0; a < 4; ++a)
        bias[a] = *(const f4*)(bi + 64 * a + hb) + *(const f4*)(bh_ + 64 * a + hb);

    // ---- zero zh (both groups, both planes: 8192 B = 2048 u32) ----
#pragma unroll
    for (int i = 0; i < 8; ++i)
        ((u32*)zh0)[tid + 256 * i] = 0u;

    f4 c0A = z4, c0B = z4;

    __syncthreads();   // drains prev-layer ws stores (vmcnt) + zh zero visible

    // ---- x prefetch pipeline (depth 2, parity reg sets, no copies) ----
    h8 bxE[2][KSX], bxO[2][KSX];
    f4 xfE[2][2], xfO[2][2];

    auto PREF = [&](int t, h8 (&bx)[2][KSX], f4 (&xf)[2][2]) {
        if constexpr (FIRST) {
#pragma unroll
            for (int g = 0; g < 2; ++g) {
                const int seq = g ? seqB : seqA;
                if (rq == 0) {
                    const float* pX = Xj + ((size_t)seq * TT + t) * NFEAT;
                    xf[g][0] = *(const f4*)pX;
                    xf[g][1] = *(const f4*)(pX + 4);
                } else {
                    xf[g][0] = z4; xf[g][1] = z4;
                }
            }
        } else {
#pragma unroll
            for (int g = 0; g < 2; ++g) {
                const int seq = g ? seqB : seqA;
                const unsigned short* pR = rbuf + ((size_t)seq * TT + t) * HID + 8 * rq;
#pragma unroll
                for (int ks = 0; ks < KSX; ++ks)
                    bx[g][ks] = *(const h8*)(pR + 32 * ks);
            }
        }
    };

    PREF(0, bxE, xfE);
    PREF(1, bxO, xfO);

    auto STEP = [&](int t, int p, h8 (&bxr)[2][KSX], f4 (&xfr)[2][2]) {
        // ---- h B-frags: issue all 4 reads up front ----
        h8 bhv[2][2];
#pragma unroll
        for (int g = 0; g < 2; ++g) {
            const char* zb = (g ? zh1 : zh0) + p * 2048;
#pragma unroll
            for (int kk = 0; kk < 2; ++kk)
                bhv[g][kk] = *(const h8*)(zb + ((cs * 128 + 64 * kk + 16 * rq) ^ swz));
        }
#pragma unroll
        for (int g = 0; g < 2; ++g) {
            // x B-frags
            h8 bx[KSX];
            if constexpr (FIRST) {
#pragma unroll
                for (int j = 0; j < 4; ++j) {
                    bx[0][j]     = (_Float16)xfr[g][0][j];
                    bx[0][4 + j] = (_Float16)xfr[g][1][j];
                }
            } else {
#pragma unroll
                for (int ks = 0; ks < KSX; ++ks) bx[ks] = bxr[g][ks];
            }

            f4 c1[4], c2[4], c3[4], c4[4];
#pragma unroll
            for (int a = 0; a < 4; ++a) {
                c1[a] = MFMA16(Ah[a][0], bx[0], bias[a], 0, 0, 0);
                c2[a] = MFMA16(Al[a][0], bx[0], z4,      0, 0, 0);
                if constexpr (KSX == 2) {
                    c1[a] = MFMA16(Ah[a][1], bx[1], c1[a], 0, 0, 0);
                    c2[a] = MFMA16(Al[a][1], bx[1], c2[a], 0, 0, 0);
                }
                c1[a] = MFMA16(Ah[a][KSX + 0], bhv[g][0], c1[a], 0, 0, 0);
                c2[a] = MFMA16(Ah[a][KSX + 1], bhv[g][1], c2[a], 0, 0, 0);
                c3[a] = MFMA16(Al[a][KSX + 0], bhv[g][0], z4,    0, 0, 0);
                c4[a] = MFMA16(Al[a][KSX + 1], bhv[g][1], z4,    0, 0, 0);
            }

            f4& c0 = g ? c0B : c0A;
            float hv[4];
#pragma unroll
            for (int r = 0; r < 4; ++r) {
                float gi = (c1[0][r] + c2[0][r]) + (c3[0][r] + c4[0][r]);
                float gf = (c1[1][r] + c2[1][r]) + (c3[1][r] + c4[1][r]);
                float gg = (c1[2][r] + c2[2][r]) + (c3[2][r] + c4[2][r]);
                float go = (c1[3][r] + c2[3][r]) + (c3[3][r] + c4[3][r]);
                float ig = sigm(gi), fg = sigm(gf), gv = tanh_(gg), og = sigm(go);
                float cc = fg * c0[r] + ig * gv;
                c0[r] = cc;
                hv[r] = og * tanh_(cc);
            }

            u64 ph = 0;
#pragma unroll
            for (int r = 0; r < 4; ++r) {
                _Float16 hh = (_Float16)hv[r];
                ph |= (u64)(*(unsigned short*)&hh) << (16 * r);
            }
            char* zb = (g ? zh1 : zh0) + (1 ^ p) * 2048;
            *(u64*)(zb + ((cs * 128 + 32 * wv + 8 * rq) ^ swz)) = ph;

            if constexpr (!LAST) {
                const int seq = g ? seqB : seqA;
                *(u64*)(wbuf + ((size_t)seq * TT + t) * HID + hb) = ph;
            } else {
                if (t == TT - 1) {
                    f4 hvec = {hv[0], hv[1], hv[2], hv[3]};
                    *(f4*)(hs + (16 * g + cs) * 68 + hb) = hvec;
                }
            }
        }
        if (t + 2 < TT) PREF(t + 2, bxr, xfr);
        RAW_BAR();
    };

#pragma unroll 1
    for (int tb = 0; tb < TT; tb += 2) {
        STEP(tb,     0, bxE, xfE);
        STEP(tb + 1, 1, bxO, xfO);
    }
}

__global__ __launch_bounds__(NTHR, 1)
void lstm_dual(const float* __restrict__ Xj,
               const float* __restrict__ Wih0, const float* __restrict__ Whh0,
               const float* __restrict__ bih0, const float* __restrict__ bhh0,
               const float* __restrict__ WihR, const float* __restrict__ WhhR,
               const float* __restrict__ bihR, const float* __restrict__ bhhR,
               const float* __restrict__ Wout, const float* __restrict__ bout,
               float* __restrict__ out,
               unsigned short* __restrict__ ws0, unsigned short* __restrict__ ws1)
{
    __shared__ char smraw[16896];
    char*  zh = smraw;                    // 2 groups x [2][16][64] fp16
    float* hs = (float*)(smraw + 8192);   // [32][68] f32

    const int tid  = threadIdx.x;
    const int seq0 = blockIdx.x * SPB;

    // layer l reads buf[(l+1)&1] (l>=1), writes buf[l&1]
    run_layer<1, true,  false>(Wih0, Whh0, bih0, bhh0, Xj, ws0, ws0, zh, hs, tid, seq0);
    run_layer<2, false, false>(WihR + (size_t)0 * 256 * HID, WhhR + (size_t)0 * 256 * HID,
                               bihR + 0 * 256, bhhR + 0 * 256, nullptr, ws0, ws1, zh, hs, tid, seq0);
    run_layer<2, false, false>(WihR + (size_t)1 * 256 * HID, WhhR + (size_t)1 * 256 * HID,
                               bihR + 1 * 256, bhhR + 1 * 256, nullptr, ws1, ws0, zh, hs, tid, seq0);
    run_layer<2, false, false>(WihR + (size_t)2 * 256 * HID, WhhR + (size_t)2 * 256 * HID,
                               bihR + 2 * 256, bhhR + 2 * 256, nullptr, ws0, ws1, zh, hs, tid, seq0);
    run_layer<2, false, true >(WihR + (size_t)3 * 256 * HID, WhhR + (size_t)3 * 256 * HID,
                               bihR + 3 * 256, bhhR + 3 * 256, nullptr, ws1, ws0, zh, hs, tid, seq0);

    __syncthreads();
    // ---- output projection: 32 seqs x 12 outs = 384 items ----
    for (int it = tid; it < SPB * TOUTC; it += NTHR) {
        int s = it / TOUTC, o = it % TOUTC;
        float sum = bout[o];
#pragma unroll 8
        for (int j = 0; j < HID; ++j)
            sum = fmaf(Wout[o * HID + j], hs[s * 68 + j], sum);
        out[(size_t)(seq0 + s) * TOUTC + o] = sum;
    }
}

extern "C" void kernel_launch(void* const* d_in, const int* in_sizes, int n_in,
                              void* d_out, int out_size, void* d_ws, size_t ws_size,
                              hipStream_t stream)
{
    const float* Xj   = (const float*)d_in[1];
    const float* Wih0 = (const float*)d_in[3];
    const float* Whh0 = (const float*)d_in[4];
    const float* bih0 = (const float*)d_in[5];
    const float* bhh0 = (const float*)d_in[6];
    const float* WihR = (const float*)d_in[7];
    const float* WhhR = (const float*)d_in[8];
    const float* bihR = (const float*)d_in[9];
    const float* bhhR = (const float*)d_in[10];
    const float* Wout = (const float*)d_in[11];
    const float* bout = (const float*)d_in[12];
    float* out = (float*)d_out;

    unsigned short* ws = (unsigned short*)d_ws;
    const size_t half_elems = (size_t)8192 * TT * HID;                 // 33.5M shorts = 67 MB
    const bool dbuf = ws_size >= 2 * half_elems * sizeof(unsigned short);
    unsigned short* ws0 = ws;
    unsigned short* ws1 = dbuf ? (ws + half_elems) : ws;               // fallback: in-place (R6-proven)

    lstm_dual<<<NBLK, NTHR, 0, stream>>>(Xj, Wih0, Whh0, bih0, bhh0,
                                         WihR, WhhR, bihR, bhhR,
                                         Wout, bout, out, ws0, ws1);
}

// Round 8
// 581.250 us; speedup vs baseline: 1.2424x; 1.2424x over previous
//
#include <hip/hip_runtime.h>
#include <cstddef>

#define HID 64
#define TT 64
#define NFEAT 8
#define TOUTC 12
#define SPB 16
#define NBLK 512
#define NTHR 256

typedef float f4 __attribute__((ext_vector_type(4)));
typedef _Float16 h8 __attribute__((ext_vector_type(8)));
typedef unsigned int u32;
typedef unsigned long long u64;

#define MFMA16 __builtin_amdgcn_mfma_f32_16x16x32_f16

__device__ __forceinline__ float sigm(float x)  { return 1.0f / (1.0f + __expf(-x)); }
__device__ __forceinline__ float tanh_(float x) { return 1.0f - 2.0f / (__expf(2.0f * x) + 1.0f); }

__device__ __forceinline__ void splitf16(const float* v, h8& hi, h8& lo) {
#pragma unroll
    for (int j = 0; j < 8; ++j) {
        _Float16 h = (_Float16)v[j];
        hi[j] = h;
        lo[j] = (_Float16)(v[j] - (float)h);
    }
}

// Barrier: drain LDS (our ds_write), raw barrier, then allow everything EXCEPT
// DS ops to be scheduled across (mask 0x7F = ALU|VALU|SALU|MFMA|VMEM|VMEMr|VMEMw;
// DS 0x80/0x100/0x200 blocked -> zh reads can't hoist above the barrier).
#define STEP_BAR() do {                                         \
    asm volatile("s_waitcnt lgkmcnt(0)" ::: "memory");          \
    __builtin_amdgcn_s_barrier();                               \
    __builtin_amdgcn_sched_barrier(0x7F);                       \
} while (0)

// LDS: zh [2][16][64] fp16 (4096 B, XOR-swizzled byte ^= (s&7)<<4), hs f32[16][68].
// ws:  fp16 [seq][t][HID] activations; dbuf across layers if ws_size allows,
//      else in-place (safe: slot (seq,t) read at step t before its write at step t).
//
// MFMA 16x16x32 f16: M = gate rows (4 tiles i,f,g,o x wave's 16 hidden units),
// N = 16 seqs, K = [x (KSX*32); h (2*32)].
// A frag: row=l&15, k=8*(l>>4)+j. B frag: col=l&15, same k. C/D: col=l&15, row=4*(l>>4)+r.
// 2 chains/gate: c1 = bias + Whi*[x;h], c2 = Wlo*[x;h]; gate = c1+c2.
template<int KSX, bool FIRST, bool LAST>
__device__ __forceinline__ void run_layer(
    const float* __restrict__ Wih, const float* __restrict__ Whh,
    const float* __restrict__ bi,  const float* __restrict__ bh_,
    const float* __restrict__ Xj,
    const unsigned short* __restrict__ rbuf, unsigned short* __restrict__ wbuf,
    char* zh, float* hs, int tid, int seq0)
{
    constexpr int NKS = KSX + 2;
    const int lane = tid & 63;
    const int wv   = tid >> 6;
    const int cs   = lane & 15;
    const int rq   = lane >> 4;
    const int hb   = 16 * wv + 4 * rq;
    const int swz  = (cs & 7) << 4;
    const int seq  = seq0 + cs;

    f4 z4 = {0.f, 0.f, 0.f, 0.f};

    // ---- weight A-fragments (fp16 hi/lo) ----
    h8 Ah[4][NKS], Al[4][NKS];
#pragma unroll
    for (int a = 0; a < 4; ++a) {
        const int row = 64 * a + 16 * wv + cs;
#pragma unroll
        for (int ks = 0; ks < NKS; ++ks) {
            float v[8];
            if (ks < KSX) {
                if (FIRST) {
                    const float* p = Wih + (size_t)row * NFEAT;
#pragma unroll
                    for (int j = 0; j < 8; ++j) v[j] = (rq == 0) ? p[j] : 0.0f;
                } else {
                    const float* p = Wih + (size_t)row * HID + 32 * ks + 8 * rq;
#pragma unroll
                    for (int j = 0; j < 8; ++j) v[j] = p[j];
                }
            } else {
                const float* p = Whh + (size_t)row * HID + 32 * (ks - KSX) + 8 * rq;
#pragma unroll
                for (int j = 0; j < 8; ++j) v[j] = p[j];
            }
            splitf16(v, Ah[a][ks], Al[a][ks]);
        }
    }

    // ---- bias (C/D layout) — used as MFMA C-init ----
    f4 bias[4];
#pragma unroll
    for (int a = 0; a < 4; ++a)
        bias[a] = *(const f4*)(bi + 64 * a + hb) + *(const f4*)(bh_ + 64 * a + hb);

    // ---- zero both zh planes (4096 B = 1024 u32) ----
#pragma unroll
    for (int i = 0; i < 4; ++i)
        ((u32*)zh)[tid * 4 + i] = 0u;

    f4 c0 = z4;

    __syncthreads();   // drains prev-layer ws stores (vmcnt) + zh zero visible

    // ---- x prefetch: depth 2, parity register sets (no copies) ----
    h8 xE[KSX], xO[KSX];   // recurrent layers
    f4 fE[2], fO[2];       // first layer (fp32 x on rq==0 lanes)

    auto PREF = [&](int t, h8 (&hx)[KSX], f4 (&fx)[2]) {
        if constexpr (FIRST) {
            if (rq == 0) {
                const float* pX = Xj + ((size_t)seq * TT + t) * NFEAT;
                fx[0] = *(const f4*)pX;
                fx[1] = *(const f4*)(pX + 4);
            } else {
                fx[0] = z4; fx[1] = z4;
            }
        } else {
            const unsigned short* pR = rbuf + ((size_t)seq * TT + t) * HID + 8 * rq;
#pragma unroll
            for (int ks = 0; ks < KSX; ++ks)
                hx[ks] = *(const h8*)(pR + 32 * ks);
        }
    };

    PREF(0, xE, fE);
    PREF(1, xO, fO);

    auto STEP = [&](int t, int p, h8 (&hx)[KSX], f4 (&fx)[2]) {
        // ---- x B-fragments from the parity regs, then refill them for t+2 ----
        h8 bx[KSX];
        if constexpr (FIRST) {
#pragma unroll
            for (int j = 0; j < 4; ++j) {
                bx[0][j]     = (_Float16)fx[0][j];
                bx[0][4 + j] = (_Float16)fx[1][j];
            }
        } else {
#pragma unroll
            for (int ks = 0; ks < KSX; ++ks) bx[ks] = hx[ks];
        }
        if (t + 2 < TT) PREF(t + 2, hx, fx);   // issued at step top: 2-step latency budget

        // ---- h B-fragments from LDS (swizzled) ----
        h8 bhh[2];
#pragma unroll
        for (int kk = 0; kk < 2; ++kk) {
            const int ho = p * 2048 + ((cs * 128 + 64 * kk + 16 * rq) ^ swz);
            bhh[kk] = *(const h8*)(zh + ho);
        }

        // ---- MFMA cluster (setprio-wrapped): 2 chains per gate, bias as C-init ----
        f4 c1[4], c2[4];
        __builtin_amdgcn_s_setprio(1);
#pragma unroll
        for (int a = 0; a < 4; ++a) {
            c1[a] = MFMA16(Ah[a][0], bx[0], bias[a], 0, 0, 0);
            c2[a] = MFMA16(Al[a][0], bx[0], z4,      0, 0, 0);
            if constexpr (KSX == 2) {
                c1[a] = MFMA16(Ah[a][1], bx[1], c1[a], 0, 0, 0);
                c2[a] = MFMA16(Al[a][1], bx[1], c2[a], 0, 0, 0);
            }
        }
#pragma unroll
        for (int a = 0; a < 4; ++a) {
            c1[a] = MFMA16(Ah[a][KSX + 0], bhh[0], c1[a], 0, 0, 0);
            c2[a] = MFMA16(Al[a][KSX + 0], bhh[0], c2[a], 0, 0, 0);
            c1[a] = MFMA16(Ah[a][KSX + 1], bhh[1], c1[a], 0, 0, 0);
            c2[a] = MFMA16(Al[a][KSX + 1], bhh[1], c2[a], 0, 0, 0);
        }
        __builtin_amdgcn_s_setprio(0);

        // ---- activations + cell update ----
        float hv[4];
#pragma unroll
        for (int r = 0; r < 4; ++r) {
            float ig = sigm(c1[0][r] + c2[0][r]);
            float fg = sigm(c1[1][r] + c2[1][r]);
            float gg = tanh_(c1[2][r] + c2[2][r]);
            float og = sigm(c1[3][r] + c2[3][r]);
            float cc = fg * c0[r] + ig * gg;
            c0[r] = cc;
            hv[r] = og * tanh_(cc);
        }

        // ---- pack h fp16 once; LDS ping write + ws store ----
        u64 ph = 0;
#pragma unroll
        for (int r = 0; r < 4; ++r) {
            _Float16 hh = (_Float16)hv[r];
            ph |= (u64)(*(unsigned short*)&hh) << (16 * r);
        }
        {
            const int wo = (1 ^ p) * 2048 + ((cs * 128 + 2 * hb) ^ swz);
            *(u64*)(zh + wo) = ph;
        }
        if constexpr (!LAST) {
            *(u64*)(wbuf + ((size_t)seq * TT + t) * HID + hb) = ph;
        } else {
            if (t == TT - 1) {
                f4 hvec = {hv[0], hv[1], hv[2], hv[3]};
                *(f4*)(hs + cs * 68 + hb) = hvec;
            }
        }

        STEP_BAR();
    };

#pragma unroll 1
    for (int tb = 0; tb < TT; tb += 2) {
        STEP(tb,     0, xE, fE);
        STEP(tb + 1, 1, xO, fO);
    }
}

__global__ __launch_bounds__(NTHR, 2)
void lstm_mfma16(const float* __restrict__ Xj,
                 const float* __restrict__ Wih0, const float* __restrict__ Whh0,
                 const float* __restrict__ bih0, const float* __restrict__ bhh0,
                 const float* __restrict__ WihR, const float* __restrict__ WhhR,
                 const float* __restrict__ bihR, const float* __restrict__ bhhR,
                 const float* __restrict__ Wout, const float* __restrict__ bout,
                 float* __restrict__ out,
                 unsigned short* __restrict__ ws0, unsigned short* __restrict__ ws1)
{
    __shared__ char smraw[8448];
    char*  zh = smraw;                    // [2][16][64] fp16
    float* hs = (float*)(smraw + 4096);   // [16][68] f32

    const int tid  = threadIdx.x;
    const int seq0 = blockIdx.x * SPB;

    // layer l>=1 reads the buffer the previous layer wrote; alternate buffers
    run_layer<1, true,  false>(Wih0, Whh0, bih0, bhh0, Xj, ws0, ws0, zh, hs, tid, seq0);
    run_layer<2, false, false>(WihR + (size_t)0 * 256 * HID, WhhR + (size_t)0 * 256 * HID,
                               bihR + 0 * 256, bhhR + 0 * 256, nullptr, ws0, ws1, zh, hs, tid, seq0);
    run_layer<2, false, false>(WihR + (size_t)1 * 256 * HID, WhhR + (size_t)1 * 256 * HID,
                               bihR + 1 * 256, bhhR + 1 * 256, nullptr, ws1, ws0, zh, hs, tid, seq0);
    run_layer<2, false, false>(WihR + (size_t)2 * 256 * HID, WhhR + (size_t)2 * 256 * HID,
                               bihR + 2 * 256, bhhR + 2 * 256, nullptr, ws0, ws1, zh, hs, tid, seq0);
    run_layer<2, false, true >(WihR + (size_t)3 * 256 * HID, WhhR + (size_t)3 * 256 * HID,
                               bihR + 3 * 256, bhhR + 3 * 256, nullptr, ws1, ws0, zh, hs, tid, seq0);

    __syncthreads();
    // ---- output projection: 16 seqs x 12 outs ----
    for (int it = tid; it < SPB * TOUTC; it += NTHR) {
        int s = it / TOUTC, o = it % TOUTC;
        float sum = bout[o];
#pragma unroll 8
        for (int j = 0; j < HID; ++j)
            sum = fmaf(Wout[o * HID + j], hs[s * 68 + j], sum);
        out[(size_t)(seq0 + s) * TOUTC + o] = sum;
    }
}

extern "C" void kernel_launch(void* const* d_in, const int* in_sizes, int n_in,
                              void* d_out, int out_size, void* d_ws, size_t ws_size,
                              hipStream_t stream)
{
    const float* Xj   = (const float*)d_in[1];
    const float* Wih0 = (const float*)d_in[3];
    const float* Whh0 = (const float*)d_in[4];
    const float* bih0 = (const float*)d_in[5];
    const float* bhh0 = (const float*)d_in[6];
    const float* WihR = (const float*)d_in[7];
    const float* WhhR = (const float*)d_in[8];
    const float* bihR = (const float*)d_in[9];
    const float* bhhR = (const float*)d_in[10];
    const float* Wout = (const float*)d_in[11];
    const float* bout = (const float*)d_in[12];
    float* out = (float*)d_out;

    unsigned short* ws = (unsigned short*)d_ws;
    const size_t half_elems = (size_t)8192 * TT * HID;   // 33.5M shorts = 67 MB
    const bool dbuf = ws_size >= 2 * half_elems * sizeof(unsigned short);
    unsigned short* ws0 = ws;
    unsigned short* ws1 = dbuf ? (ws + half_elems) : ws;   // in-place fallback (R6-proven)

    lstm_mfma16<<<NBLK, NTHR, 0, stream>>>(Xj, Wih0, Whh0, bih0, bhh0,
                                           WihR, WhhR, bihR, bhhR,
                                           Wout, bout, out, ws0, ws1);
}